// Round 7
// baseline (600.945 us; speedup 1.0000x reference)
//
#include <hip/hip_runtime.h>
#include <stdint.h>

#define DD 1024
#define BATCH 32768

typedef unsigned short u16;
typedef __attribute__((ext_vector_type(8))) __bf16 bf16x8;
typedef __attribute__((ext_vector_type(4))) float f32x4;
typedef __attribute__((ext_vector_type(4))) unsigned int u32x4;

__device__ __forceinline__ u16 f2bf(float x) {
  unsigned int u = __builtin_bit_cast(unsigned int, x);
  u = u + 0x7FFFu + ((u >> 16) & 1u);   // round-to-nearest-even
  return (u16)(u >> 16);
}

// One merged convert kernel: input (2048 blks), hidden (2048), 6 weights (64 each).
__global__ void cvt_all(const float4* __restrict__ in0, const float4* __restrict__ in1,
                        const float4* __restrict__ w0, const float4* __restrict__ w1,
                        const float4* __restrict__ w2, const float4* __restrict__ w3,
                        const float4* __restrict__ w4, const float4* __restrict__ w5,
                        ushort4* __restrict__ o0, ushort4* __restrict__ o1,
                        ushort4* __restrict__ ow) {
  int b = blockIdx.x;
  const float4* s; ushort4* d; int rel;
  if (b < 2048)      { s = in0; d = o0; rel = b; }
  else if (b < 4096) { s = in1; d = o1; rel = b - 2048; }
  else {
    int t = b - 4096; int g = t >> 6; rel = t & 63;
    s = (g == 0) ? w0 : (g == 1) ? w1 : (g == 2) ? w2 : (g == 3) ? w3 : (g == 4) ? w4 : w5;
    d = ow + (size_t)g * 262144;
  }
  int i0 = rel * 4096 + threadIdx.x;
#pragma unroll
  for (int j = 0; j < 16; ++j) {
    int i = i0 + j * 256;
    float4 v = s[i];
    ushort4 o;
    o.x = f2bf(v.x); o.y = f2bf(v.y); o.z = f2bf(v.z); o.w = f2bf(v.w);
    d[i] = o;
  }
}

// -------- fused GRU GEMM: 2 blocks/CU + counted-vmcnt double buffer ---------
// Tile: BM=128, BN=64, BK=32. 256 thr = 4 waves (2M x 2N), wave tile 64x32.
// Per-buffer LDS (u16): A_in[128][32] @0, A_h @4096, W[g][64][32] @8192+g*2048
// = 20480 u16 (40KB); dbuf = 80KB -> 2 blocks/CU (8 waves, register-capped
// anyway: 128 AGPR acc + ~110 VGPR ~= 250 regs -> 8 waves/CU max).
// Swizzle (R2-measured ZERO conflicts at this exact geometry): 64B rows;
// natural k-slot k (of 4) of row R stored at slot k ^ ((R>>1)&3); staging
// fetches pre-swizzled so LDS dest stays linear; reads use
// sl = kb ^ ((r15>>1)&3)  (16x16 pattern: 8 consecutive lanes = 8 rows).
//
// Pipeline per kt: vmcnt(10)=tile kt's loads done (kt+1's 10 stay in flight,
// T4) -> barrier -> 20 ds_reads + lgkm + 48 MFMA -> barrier -> stage(kt+2).
#define BUF_U 20480

__device__ __forceinline__ bf16x8 ld8(const u16* p) {
  u32x4 v = *reinterpret_cast<const u32x4*>(p);
  return __builtin_bit_cast(bf16x8, v);
}

__device__ __forceinline__ f32x4 mfma16(bf16x8 a, bf16x8 b, f32x4 c) {
  return __builtin_amdgcn_mfma_f32_16x16x32_bf16(a, b, c, 0, 0, 0);
}

__device__ __forceinline__ void stage_one(const u16* src, const u16* dst) {
  __builtin_amdgcn_global_load_lds(
      (const __attribute__((address_space(1))) void*)src,
      (__attribute__((address_space(3))) void*)dst, 16, 0, 0);
}

__global__ __launch_bounds__(256, 2) void gru_fused(
    const u16* __restrict__ ain, const u16* __restrict__ ah,
    const u16* __restrict__ wall, const float* __restrict__ hidf,
    const float* __restrict__ b_ir, const float* __restrict__ b_hr,
    const float* __restrict__ b_iz, const float* __restrict__ b_hz,
    const float* __restrict__ b_in, const float* __restrict__ b_hn,
    float* __restrict__ out) {
  __shared__ __align__(16) u16 lds[2 * BUF_U];  // 80 KB

  int bid = blockIdx.x;
  // XCD mapping (R4/R5-verified, FETCH 1.18 -> 0.55-0.84 GB): XCD x owns mb
  // range [x*32, x*32+32); 16 consecutive blocks share one A-panel (L2-hot).
  int x = bid & 7;
  int s = bid >> 3;              // 0..511
  int mb = (x << 5) | (s >> 4);  // 0..255
  int nb = s & 15;               // 0..15

  int tid = threadIdx.x;
  int wid = tid >> 6;
  int lane = tid & 63;
  int r15 = lane & 15;
  int kb = lane >> 4;
  int wm = wid >> 1;   // 0..1
  int wn = wid & 1;    // 0..1

  const f32x4 zero = {0.f, 0.f, 0.f, 0.f};
  f32x4 acc_r[4][2], acc_z[4][2], acc_n[4][2], acc_hn[4][2];
#pragma unroll
  for (int i = 0; i < 4; ++i)
#pragma unroll
    for (int j = 0; j < 2; ++j) {
      acc_r[i][j] = zero; acc_z[i][j] = zero;
      acc_n[i][j] = zero; acc_hn[i][j] = zero;
    }

  // Staging: chunk = 1KB = 16 rows x 64B; lane l -> row l>>2, slot l&3;
  // global k-slot pre-swizzled: (l&3) ^ ((l>>3)&3) = (l&3) ^ ((row>>1)&3).
  int lrow = lane >> 2;
  unsigned koff = (unsigned)((((lane & 3) ^ ((lane >> 3) & 3))) << 3);
  const u16* ain_r = ain + (unsigned)(mb * 128 + lrow) * DD + koff;
  const u16* ah_r  = ah  + (unsigned)(mb * 128 + lrow) * DD + koff;
  // W chunks: cw = wid + 4j (j=0..5): gate g = cw>>2, row-chunk c = cw&3.
  const u16* w_rr  = wall + (unsigned)(nb * 64 + lrow) * DD + koff;

  // 10 gloads per thread per tile: 2 A_in, 2 A_h, 6 W.
  auto stage = [&](int kt) {
    unsigned kc = (unsigned)(kt << 5);
    int base = (kt & 1) * BUF_U;
#pragma unroll
    for (int j = 0; j < 2; ++j) {
      int c = wid + (j << 2);    // chunk 0..7 (16 rows each)
      stage_one(ain_r + (unsigned)(c * 16) * DD + kc, &lds[base + c * 512]);
      stage_one(ah_r  + (unsigned)(c * 16) * DD + kc, &lds[base + 4096 + c * 512]);
    }
#pragma unroll
    for (int j = 0; j < 6; ++j) {
      int cw = wid + (j << 2);   // 0..23
      int g = cw >> 2, c = cw & 3;
      stage_one(w_rr + (((unsigned)g << 20) + (unsigned)(c * 16) * DD) + kc,
                &lds[base + 8192 + g * 2048 + c * 512]);
    }
  };

  // Read-side swizzled slot (R2-proven): sl = kb ^ ((r15>>1)&3).
  int slx = (kb ^ ((r15 >> 1) & 3)) << 3;

  bf16x8 afi[4], afh[4], bw[6];

  stage(0); stage(1);   // 20 loads in flight
  for (int kt = 0; kt < 32; ++kt) {
    if (kt < 31) {
      asm volatile("s_waitcnt vmcnt(10)" ::: "memory");  // tile kt ready
    } else {
      asm volatile("s_waitcnt vmcnt(0)" ::: "memory");
    }
    __builtin_amdgcn_s_barrier();
    __builtin_amdgcn_sched_barrier(0);

    const u16* B = &lds[(kt & 1) * BUF_U];
#pragma unroll
    for (int i = 0; i < 4; ++i) {
      int Rm = (wm << 6) + (i << 4) + r15;
      afi[i] = ld8(B + Rm * 32 + slx);
      afh[i] = ld8(B + 4096 + Rm * 32 + slx);
    }
#pragma unroll
    for (int jf = 0; jf < 2; ++jf) {
      int Rn = (wn << 5) + (jf << 4) + r15;
      const u16* W0 = B + 8192 + Rn * 32 + slx;
#pragma unroll
      for (int g = 0; g < 6; ++g) bw[g] = ld8(W0 + g * 2048);
      asm volatile("s_waitcnt lgkmcnt(0)" ::: "memory");
      __builtin_amdgcn_sched_barrier(0);   // rule #18
      __builtin_amdgcn_s_setprio(1);
#pragma unroll
      for (int i = 0; i < 4; ++i) {
        acc_r[i][jf]  = mfma16(afi[i], bw[0], acc_r[i][jf]);
        acc_r[i][jf]  = mfma16(afh[i], bw[1], acc_r[i][jf]);
        acc_z[i][jf]  = mfma16(afi[i], bw[2], acc_z[i][jf]);
        acc_z[i][jf]  = mfma16(afh[i], bw[3], acc_z[i][jf]);
        acc_n[i][jf]  = mfma16(afi[i], bw[4], acc_n[i][jf]);
        acc_hn[i][jf] = mfma16(afh[i], bw[5], acc_hn[i][jf]);
      }
      __builtin_amdgcn_s_setprio(0);
    }
    __builtin_amdgcn_s_barrier();     // all reads of buf[kt] done
    if (kt < 30) stage(kt + 2);       // overwrite buf[kt] for tile kt+2
  }

  // ---- fused epilogue: gates + residual + dual store ----
  // C/D layout: col = lane&15, row = (lane>>4)*4 + q
#pragma unroll
  for (int jf = 0; jf < 2; ++jf) {
    int col = (nb << 6) + (wn << 5) + (jf << 4) + r15;
    float brc = b_ir[col] + b_hr[col];
    float bzc = b_iz[col] + b_hz[col];
    float bnc = b_in[col];
    float bhc = b_hn[col];
#pragma unroll
    for (int i = 0; i < 4; ++i) {
      int row0 = (mb << 7) + (wm << 6) + (i << 4) + (kb << 2);
#pragma unroll
      for (int q = 0; q < 4; ++q) {
        int row = row0 + q;
        float vr = acc_r[i][jf][q] + brc;
        float vz = acc_z[i][jf][q] + bzc;
        float vn = acc_n[i][jf][q] + bnc;
        float vh = acc_hn[i][jf][q] + bhc;
        float rg = __builtin_amdgcn_rcpf(1.f + __expf(-vr));
        float zg = __builtin_amdgcn_rcpf(1.f + __expf(-vz));
        float pre = vn + rg * vh;
        float ax = fabsf(pre);
        float e2 = __expf(-2.f * ax);
        float th = copysignf((1.f - e2) * __builtin_amdgcn_rcpf(1.f + e2), pre);
        float hp = hidf[((size_t)row << 10) + col];
        float h = (1.f - zg) * th + zg * hp;
        size_t o = ((size_t)row << 10) + col;
        out[o] = h;
        out[o + (size_t)BATCH * DD] = h;  // tuple (h, h)
      }
    }
  }
}

extern "C" void kernel_launch(void* const* d_in, const int* in_sizes, int n_in,
                              void* d_out, int out_size, void* d_ws, size_t ws_size,
                              hipStream_t stream) {
  (void)in_sizes; (void)n_in; (void)out_size; (void)ws_size;
  const float* inp = (const float*)d_in[0];
  const float* hid = (const float*)d_in[1];
  u16* ws_in  = (u16*)d_ws;
  u16* ws_hid = ws_in + (size_t)BATCH * DD;
  u16* ws_w   = ws_hid + (size_t)BATCH * DD;

  hipLaunchKernelGGL(cvt_all, dim3(4480), dim3(256), 0, stream,
                     (const float4*)inp, (const float4*)hid,
                     (const float4*)d_in[2], (const float4*)d_in[4],
                     (const float4*)d_in[6], (const float4*)d_in[8],
                     (const float4*)d_in[10], (const float4*)d_in[12],
                     (ushort4*)ws_in, (ushort4*)ws_hid, (ushort4*)ws_w);

  hipLaunchKernelGGL(gru_fused, dim3(4096), dim3(256), 0, stream,
                     ws_in, ws_hid, ws_w, hid,
                     (const float*)d_in[3], (const float*)d_in[5],
                     (const float*)d_in[7], (const float*)d_in[9],
                     (const float*)d_in[11], (const float*)d_in[13],
                     (float*)d_out);
}

// Round 9
// 498.197 us; speedup vs baseline: 1.2062x; 1.2062x over previous
//
#include <hip/hip_runtime.h>
#include <stdint.h>

#define DD 1024
#define BATCH 32768

typedef unsigned short u16;
typedef __attribute__((ext_vector_type(8))) __bf16 bf16x8;
typedef __attribute__((ext_vector_type(4))) float f32x4;
typedef __attribute__((ext_vector_type(4))) float fv4;       // ext-vector for nontemporal builtins
typedef __attribute__((ext_vector_type(4))) u16 u16x4;
typedef __attribute__((ext_vector_type(4))) unsigned int u32x4;

__device__ __forceinline__ u16 f2bf(float x) {
  unsigned int u = __builtin_bit_cast(unsigned int, x);
  u = u + 0x7FFFu + ((u >> 16) & 1u);   // round-to-nearest-even
  return (u16)(u >> 16);
}

__device__ __forceinline__ float bf2f(u16 x) {
  unsigned int u = ((unsigned int)x) << 16;
  return __builtin_bit_cast(float, u);
}

// One merged convert kernel: input (2048 blks), hidden (2048), 6 weights (64 each).
// Sources are dead after this pass -> nontemporal loads (don't pollute L2/L3);
// destinations are re-read by the GEMM -> normal (cacheable) stores.
__global__ void cvt_all(const fv4* __restrict__ in0, const fv4* __restrict__ in1,
                        const fv4* __restrict__ w0, const fv4* __restrict__ w1,
                        const fv4* __restrict__ w2, const fv4* __restrict__ w3,
                        const fv4* __restrict__ w4, const fv4* __restrict__ w5,
                        u16x4* __restrict__ o0, u16x4* __restrict__ o1,
                        u16x4* __restrict__ ow) {
  int b = blockIdx.x;
  const fv4* s; u16x4* d; int rel;
  if (b < 2048)      { s = in0; d = o0; rel = b; }
  else if (b < 4096) { s = in1; d = o1; rel = b - 2048; }
  else {
    int t = b - 4096; int g = t >> 6; rel = t & 63;
    s = (g == 0) ? w0 : (g == 1) ? w1 : (g == 2) ? w2 : (g == 3) ? w3 : (g == 4) ? w4 : w5;
    d = ow + (size_t)g * 262144;
  }
  int i0 = rel * 4096 + threadIdx.x;
#pragma unroll
  for (int j = 0; j < 16; ++j) {
    int i = i0 + j * 256;
    fv4 v = __builtin_nontemporal_load(&s[i]);
    u16x4 o;
    o.x = f2bf(v.x); o.y = f2bf(v.y); o.z = f2bf(v.z); o.w = f2bf(v.w);
    d[i] = o;
  }
}

// ---------------- fused GRU GEMM (R0 structure, proven 466 us) ----------------
// Tile: BM=128, BN=64, BK=64. 256 thr = 4 waves (2M x 2N), wave tile 64x32.
// LDS (u16): A_in[128][64] @0, A_h[128][64] @8192, W[g][64][64] @16384+g*4096.
// 80 KB -> 2 blocks/CU: the m114 implicit cross-block overlap regime; R1-R6
// showed every explicit pipeline variant loses to this at 128-tile scale.
// Swizzle (R0-measured ZERO conflicts): 128B rows, 8x 16B slots; natural
// k-slot k of row R stored at slot k ^ (R&7); staging pre-swizzles the global
// source so the LDS dest stays linear (global_load_lds requirement).
#define A_IN_U 0
#define A_H_U  8192
#define W_U(g) (16384 + (g) * 4096)

__device__ __forceinline__ bf16x8 ld8(const u16* p) {
  u32x4 v = *reinterpret_cast<const u32x4*>(p);
  return __builtin_bit_cast(bf16x8, v);
}

__device__ __forceinline__ f32x4 mfma16(bf16x8 a, bf16x8 b, f32x4 c) {
  return __builtin_amdgcn_mfma_f32_16x16x32_bf16(a, b, c, 0, 0, 0);
}

__device__ __forceinline__ void stage_chunk(const u16* grow, u16* ldsdst) {
  int l = threadIdx.x & 63;
  int r = l >> 3;
  int s = l & 7;
  const u16* src = grow + r * DD + ((s ^ r) << 3);
  __builtin_amdgcn_global_load_lds(
      (const __attribute__((address_space(1))) void*)src,
      (__attribute__((address_space(3))) void*)ldsdst, 16, 0, 0);
}

__global__ __launch_bounds__(256, 2) void gru_fused(
    const u16* __restrict__ ain, const u16* __restrict__ ah,
    const u16* __restrict__ wall, const u16* __restrict__ hidb,
    const float* __restrict__ b_ir, const float* __restrict__ b_hr,
    const float* __restrict__ b_iz, const float* __restrict__ b_hz,
    const float* __restrict__ b_in, const float* __restrict__ b_hn,
    float* __restrict__ out) {
  __shared__ __align__(16) u16 lds[40960];  // 80 KB

  int bid = blockIdx.x;
  // R0's XCD mapping (proven with the 466 us run): XCD x owns nb in {2x,2x+1}
  // -> its 1.5 MB W column-slice stays L2-resident; W is 12 of the 20 staged
  // loads per thread, so the majority load class is L2-hot.
  int wg = ((bid & 7) << 9) | (bid >> 3);
  int nb = wg >> 8;    // 0..15   (64-col slice of D)
  int mb = wg & 255;   // 0..255  (128-row slice of batch)

  int tid = threadIdx.x;
  int wid = tid >> 6;
  int lane = tid & 63;
  int r15 = lane & 15;
  int kb = lane >> 4;
  int wm = wid >> 1;   // 2x2 wave grid, wave tile 64x32
  int wn = wid & 1;

  const f32x4 zero = {0.f, 0.f, 0.f, 0.f};
  f32x4 acc_r[4][2], acc_z[4][2], acc_n[4][2], acc_hn[4][2];
#pragma unroll
  for (int i = 0; i < 4; ++i)
#pragma unroll
    for (int j = 0; j < 2; ++j) {
      acc_r[i][j] = zero; acc_z[i][j] = zero;
      acc_n[i][j] = zero; acc_hn[i][j] = zero;
    }

  const u16* ain_t = ain + ((size_t)(mb * 128) << 10);
  const u16* ah_t  = ah  + ((size_t)(mb * 128) << 10);
  const u16* w_t   = wall + ((size_t)(nb * 64) << 10);

  for (int kt = 0; kt < 16; ++kt) {
    int kcol = kt << 6;
    __syncthreads();  // previous iter's compute done before overwrite
    // A tiles: 16 chunks each, 4 per wave
#pragma unroll
    for (int j = 0; j < 4; ++j) {
      int c = (j << 2) | wid;
      stage_chunk(ain_t + ((size_t)c << 13) + kcol, &lds[A_IN_U + c * 512]);
      stage_chunk(ah_t  + ((size_t)c << 13) + kcol, &lds[A_H_U  + c * 512]);
    }
    // W tiles: 8 chunks each, 2 per wave
#pragma unroll
    for (int g = 0; g < 6; ++g) {
      const u16* wg_t = w_t + ((size_t)g << 20) + kcol;
#pragma unroll
      for (int j = 0; j < 2; ++j) {
        int c = (j << 2) | wid;
        stage_chunk(wg_t + ((size_t)c << 13), &lds[W_U(g) + c * 512]);
      }
    }
    __syncthreads();  // drain; co-resident block computes meanwhile (m114)

#pragma unroll
    for (int ks = 0; ks < 2; ++ks) {
      bf16x8 afi[4], afh[4];
#pragma unroll
      for (int i = 0; i < 4; ++i) {
        int Rm = (wm << 6) + (i << 4) + r15;
        int sl = ((ks << 2) | kb) ^ (Rm & 7);
        afi[i] = ld8(&lds[A_IN_U + Rm * 64 + sl * 8]);
        afh[i] = ld8(&lds[A_H_U  + Rm * 64 + sl * 8]);
      }
#pragma unroll
      for (int jf = 0; jf < 2; ++jf) {
        int Rn = (wn << 5) + (jf << 4) + r15;
        int sl = ((ks << 2) | kb) ^ (Rn & 7);
        bf16x8 bir = ld8(&lds[W_U(0) + Rn * 64 + sl * 8]);
        bf16x8 bhr = ld8(&lds[W_U(1) + Rn * 64 + sl * 8]);
        bf16x8 biz = ld8(&lds[W_U(2) + Rn * 64 + sl * 8]);
        bf16x8 bhz = ld8(&lds[W_U(3) + Rn * 64 + sl * 8]);
        bf16x8 bin = ld8(&lds[W_U(4) + Rn * 64 + sl * 8]);
        bf16x8 bhn = ld8(&lds[W_U(5) + Rn * 64 + sl * 8]);
#pragma unroll
        for (int i = 0; i < 4; ++i) {
          acc_r[i][jf]  = mfma16(afi[i], bir, acc_r[i][jf]);
          acc_r[i][jf]  = mfma16(afh[i], bhr, acc_r[i][jf]);
          acc_z[i][jf]  = mfma16(afi[i], biz, acc_z[i][jf]);
          acc_z[i][jf]  = mfma16(afh[i], bhz, acc_z[i][jf]);
          acc_n[i][jf]  = mfma16(afi[i], bin, acc_n[i][jf]);
          acc_hn[i][jf] = mfma16(afh[i], bhn, acc_hn[i][jf]);
        }
      }
    }
  }

  // ---- fused epilogue: gates + residual + dual nontemporal store ----
  // C/D layout (m89-verified): col = lane&15, row = (lane>>4)*4 + reg
#pragma unroll
  for (int jf = 0; jf < 2; ++jf) {
    int col = (nb << 6) + (wn << 5) + (jf << 4) + r15;
    float brc = b_ir[col] + b_hr[col];
    float bzc = b_iz[col] + b_hz[col];
    float bnc = b_in[col];
    float bhc = b_hn[col];
#pragma unroll
    for (int i = 0; i < 4; ++i) {
      int row0 = (mb << 7) + (wm << 6) + (i << 4) + (kb << 2);
#pragma unroll
      for (int q = 0; q < 4; ++q) {
        int row = row0 + q;
        float vr = acc_r[i][jf][q] + brc;
        float vz = acc_z[i][jf][q] + bzc;
        float vn = acc_n[i][jf][q] + bnc;
        float vh = acc_hn[i][jf][q] + bhc;
        float rg = __builtin_amdgcn_rcpf(1.f + __expf(-vr));
        float zg = __builtin_amdgcn_rcpf(1.f + __expf(-vz));
        float pre = vn + rg * vh;
        float ax = fabsf(pre);
        float e2 = __expf(-2.f * ax);
        float th = copysignf((1.f - e2) * __builtin_amdgcn_rcpf(1.f + e2), pre);
        float hp = bf2f(hidb[((size_t)row << 10) + col]);  // bf16 hidden (64MB)
        float h = (1.f - zg) * th + zg * hp;
        size_t o = ((size_t)row << 10) + col;
        __builtin_nontemporal_store(h, &out[o]);
        __builtin_nontemporal_store(h, &out[o + (size_t)BATCH * DD]);  // (h, h)
      }
    }
  }
}

extern "C" void kernel_launch(void* const* d_in, const int* in_sizes, int n_in,
                              void* d_out, int out_size, void* d_ws, size_t ws_size,
                              hipStream_t stream) {
  (void)in_sizes; (void)n_in; (void)out_size; (void)ws_size;
  const float* inp = (const float*)d_in[0];
  const float* hid = (const float*)d_in[1];
  // ws: [input bf16 64MB][hidden bf16 64MB][W_ir..W_hn bf16 12MB]
  u16* ws_in  = (u16*)d_ws;
  u16* ws_hid = ws_in + (size_t)BATCH * DD;
  u16* ws_w   = ws_hid + (size_t)BATCH * DD;

  hipLaunchKernelGGL(cvt_all, dim3(4480), dim3(256), 0, stream,
                     (const fv4*)inp, (const fv4*)hid,
                     (const fv4*)d_in[2], (const fv4*)d_in[4],
                     (const fv4*)d_in[6], (const fv4*)d_in[8],
                     (const fv4*)d_in[10], (const fv4*)d_in[12],
                     (u16x4*)ws_in, (u16x4*)ws_hid, (u16x4*)ws_w);

  hipLaunchKernelGGL(gru_fused, dim3(4096), dim3(256), 0, stream,
                     ws_in, ws_hid, ws_w, ws_hid,
                     (const float*)d_in[3], (const float*)d_in[5],
                     (const float*)d_in[7], (const float*)d_in[9],
                     (const float*)d_in[11], (const float*)d_in[13],
                     (float*)d_out);
}